// Round 9
// baseline (166.528 us; speedup 1.0000x reference)
//
#include <hip/hip_runtime.h>
#include <hip/hip_bf16.h>
#include <cstdint>

#define SEQ   720
#define PRED  720
#define CH    862
#define NB    64
#define NIN   360   // IN_LEN
#define KP    384   // padded K (12 * 32)
#define CP    896   // padded channels (7 * 128)
#define PP    768   // padded pred (6 * 128)
#define BK    32

typedef __attribute__((ext_vector_type(8))) short s16x8;
typedef __attribute__((ext_vector_type(4))) float f32x4;
typedef __attribute__((ext_vector_type(2))) float f32x2;
typedef unsigned int u32;
typedef unsigned short u16;

__device__ __forceinline__ u16 to_bf16u(float f){
  __hip_bfloat16 h = __float2bfloat16(f);
  return *reinterpret_cast<u16*>(&h);
}

// ---------------- Kernel A: DCT-II ortho matrix D[n][m], n,m in [0,360) ----------------
__global__ __launch_bounds__(256) void k_dct(float* __restrict__ Dm){
  int idx = blockIdx.x*256 + threadIdx.x;
  if (idx >= NIN*NIN) return;
  int n = idx / NIN, m = idx % NIN;
  int r = ((2*m+1)*n) % (4*NIN);
  float ang = (float)r * (float)(3.14159265358979323846 / 720.0);
  float v = cosf(ang) * 0.07453559924999299f;   // sqrt(2/360)
  if (n == 0) v *= 0.7071067811865476f;
  Dm[idx] = v;
}

// ---------------- Kernel B: M[p][m] = (1/N) sum_n Wlo[p][n] * D[n][m]  (bf16) + row sums ----------------
__global__ __launch_bounds__(384) void k_mmat(const float* __restrict__ Wlo, const float* __restrict__ Dm,
                                              u16* __restrict__ Mbf, float* __restrict__ Srow,
                                              float* __restrict__ Slo){
  int p = blockIdx.x;
  int t = threadIdx.x;
  if (p >= PRED){
    Mbf[(size_t)p*KP + t] = 0;
    if (t == 0){ Srow[p] = 0.f; Slo[p] = 0.f; }
    return;
  }
  __shared__ float Wrow[NIN];
  __shared__ float redM[6], redW[6];
  if (t < NIN) Wrow[t] = Wlo[(size_t)p*NIN + t];
  __syncthreads();
  float acc = 0.f;
  if (t < NIN){
    const float* Dc = Dm + t;
    #pragma unroll 4
    for (int n = 0; n < NIN; n++) acc += Wrow[n] * Dc[(size_t)n*NIN];
    acc *= (1.0f/360.0f);
  }
  Mbf[(size_t)p*KP + t] = (t < NIN) ? to_bf16u(acc) : (u16)0;
  float mv = (t < NIN) ? acc : 0.f;
  float wv = (t < NIN) ? Wrow[t] : 0.f;
  #pragma unroll
  for (int off = 32; off > 0; off >>= 1){
    mv += __shfl_down(mv, off);
    wv += __shfl_down(wv, off);
  }
  int wid = t >> 6, lid = t & 63;
  if (lid == 0){ redM[wid] = mv; redW[wid] = wv; }
  __syncthreads();
  if (t == 0){
    float sm = 0.f, sw = 0.f;
    #pragma unroll
    for (int i = 0; i < 6; i++){ sm += redM[i]; sw += redW[i]; }
    Srow[p] = sm; Slo[p] = sw;
  }
}

// ---------------- Kernel C: pair sums -> bf16 A-matrix [NB*CP][KP], + per-(b,c) mean ----------------
__global__ __launch_bounds__(256) void k_pre(const float* __restrict__ x, u16* __restrict__ pairB,
                                             float* __restrict__ meanw){
  int b  = blockIdx.y;
  int c0 = blockIdx.x * 64;
  int t  = threadIdx.x;
  int c16  = t & 15;
  int mrow = t >> 4;
  int w    = t >> 6;
  __shared__ u16  pl[NIN][66];
  __shared__ float red[4][64];
  const float rs2 = 0.7071067811865476f;
  int cb = c0 + c16*4;
  bool full = (cb + 3 < CH);
  const float* xb = x + (size_t)b*SEQ*CH + cb;
  float s0=0.f, s1=0.f, s2=0.f, s3=0.f;

  for (int m = mrow; m < NIN; m += 16){
    const float* r0 = xb + (size_t)(2*m)*CH;
    float a0,a1,a2,a3, e0,e1,e2,e3;
    if (full){
      f32x4 va = *reinterpret_cast<const f32x4*>(r0);
      f32x2 vb = *reinterpret_cast<const f32x2*>(r0 + CH);
      f32x2 vc = *reinterpret_cast<const f32x2*>(r0 + CH + 2);
      a0=va.x; a1=va.y; a2=va.z; a3=va.w;
      e0=vb.x; e1=vb.y; e2=vc.x; e3=vc.y;
    } else {
      a0 = (cb+0<CH)? r0[0]:0.f; a1 = (cb+1<CH)? r0[1]:0.f;
      a2 = (cb+2<CH)? r0[2]:0.f; a3 = (cb+3<CH)? r0[3]:0.f;
      e0 = (cb+0<CH)? r0[CH+0]:0.f; e1 = (cb+1<CH)? r0[CH+1]:0.f;
      e2 = (cb+2<CH)? r0[CH+2]:0.f; e3 = (cb+3<CH)? r0[CH+3]:0.f;
    }
    float p0=a0+e0, p1=a1+e1, p2=a2+e2, p3=a3+e3;
    s0+=p0; s1+=p1; s2+=p2; s3+=p3;
    u32 lo = (u32)to_bf16u(p0*rs2) | ((u32)to_bf16u(p1*rs2) << 16);
    u32 hi = (u32)to_bf16u(p2*rs2) | ((u32)to_bf16u(p3*rs2) << 16);
    *reinterpret_cast<u32*>(&pl[m][c16*4 + 0]) = lo;
    *reinterpret_cast<u32*>(&pl[m][c16*4 + 2]) = hi;
  }

  s0 += __shfl_down(s0, 32); s1 += __shfl_down(s1, 32);
  s2 += __shfl_down(s2, 32); s3 += __shfl_down(s3, 32);
  s0 += __shfl_down(s0, 16); s1 += __shfl_down(s1, 16);
  s2 += __shfl_down(s2, 16); s3 += __shfl_down(s3, 16);
  if ((t & 63) < 16){
    f32x4 rv; rv.x=s0; rv.y=s1; rv.z=s2; rv.w=s3;
    *reinterpret_cast<f32x4*>(&red[w][c16*4]) = rv;
  }
  __syncthreads();
  if (t < 64){
    float mean = (red[0][t] + red[1][t] + red[2][t] + red[3][t]) * (1.0f/SEQ);
    meanw[(size_t)b*CP + c0 + t] = mean;
  }

  int rowc = t >> 2;
  int mq0  = t & 3;
  size_t rbase = ((size_t)b*CP + c0 + rowc) * KP;
  for (int i = 0; i < 12; i++){
    int mg = mq0 + 4*i;
    u16 vals[8];
    #pragma unroll
    for (int j = 0; j < 8; j++){
      int m = mg*8 + j;
      vals[j] = (m < NIN) ? pl[m][rowc] : (u16)0;
    }
    uint4 pk;
    pk.x = (u32)vals[0] | ((u32)vals[1] << 16);
    pk.y = (u32)vals[2] | ((u32)vals[3] << 16);
    pk.z = (u32)vals[4] | ((u32)vals[5] << 16);
    pk.w = (u32)vals[6] | ((u32)vals[7] << 16);
    *reinterpret_cast<uint4*>(pairB + rbase + (size_t)mg*8) = pk;
  }
}

// ---------------- Kernel D: GEMM G = A * M^T (+ fused epilogue) ----------------
#define GLOAD_LDS16(gp, lp_) __builtin_amdgcn_global_load_lds( \
    (const __attribute__((address_space(1))) u32*)(gp), \
    (__attribute__((address_space(3))) u32*)(lp_), 16, 0, 0)

__global__ __launch_bounds__(256, 4) void k_gemm(const u16* __restrict__ Apack, const u16* __restrict__ Mbf,
                                              const float* __restrict__ Srow, const float* __restrict__ Slo,
                                              const float* __restrict__ meanw,
                                              const float* __restrict__ w1, const float* __restrict__ b1,
                                              const float* __restrict__ w2, const float* __restrict__ b2,
                                              const float* __restrict__ blo,
                                              float* __restrict__ out){
  // XCD-aware bijective swizzle: 2688 = 8 * 336.
  int bid = blockIdx.x;
  int idx = (bid & 7) * 336 + (bid >> 3);
  int pt  = idx % 6;
  int rem = idx / 6;
  int ct  = rem % 7;
  int b   = rem / 7;

  int t  = threadIdx.x;
  int w  = t >> 6, l = t & 63;
  int wr = w >> 1, wc = w & 1;

  // 48 KB: As[3]+Bs[3] (triple-buffer ring, 2 tiles in flight); wbuf unions on top in epilogue.
  __shared__ __align__(16) char smem[49152];
  u16 (*As)[128*BK] = reinterpret_cast<u16(*)[128*BK]>(smem);
  u16 (*Bs)[128*BK] = reinterpret_cast<u16(*)[128*BK]>(smem + 24576);
  float (*wbuf)[16][132] = reinterpret_cast<float(*)[16][132]>(smem);  // [wc][p16][c128+pad]

  f32x4 acc[4][4] = {};

  const u16* Abase = Apack + ((size_t)b*CP + (size_t)ct*128) * KP;
  const u16* Bbase = Mbf + (size_t)pt*128*KP;
  int srow = t >> 2;
  int squad = t & 3;
  int row16 = l & 15, kb = l >> 4;
  int sperm = (srow >> 1) & 3;        // write-side XOR swizzle (global src pre-swizzled)
  int rperm = (row16 >> 1) & 3;       // read-side XOR swizzle (same involution)

#define STAGE(bufi, k0) do { \
    GLOAD_LDS16(Abase + (size_t)(srow)*KP + (k0) + ((squad^sperm))*8,      &As[bufi][(srow)*BK + squad*8]); \
    GLOAD_LDS16(Abase + (size_t)(64 + srow)*KP + (k0) + ((squad^sperm))*8, &As[bufi][(64 + srow)*BK + squad*8]); \
    GLOAD_LDS16(Bbase + (size_t)(srow)*KP + (k0) + ((squad^sperm))*8,      &Bs[bufi][(srow)*BK + squad*8]); \
    GLOAD_LDS16(Bbase + (size_t)(64 + srow)*KP + (k0) + ((squad^sperm))*8, &Bs[bufi][(64 + srow)*BK + squad*8]); \
  } while(0)

  // Pipeline depth 2: buffers ks%3; iter ks stages tile ks+2 (overwrites buf used at ks-1,
  // safe past the end-of-iter-(ks-1) barrier), then waits vmcnt(8) so tile ks is resident
  // while tiles ks+1, ks+2 (8 loads) stay in flight.
  STAGE(0, 0);
  STAGE(1, BK);
  for (int ks = 0; ks < 12; ks++){
    int cur = ks % 3;
    if (ks < 10){
      STAGE((ks + 2) % 3, (ks + 2) * BK);
      asm volatile("s_waitcnt vmcnt(8)" ::: "memory");
    } else if (ks == 10){
      asm volatile("s_waitcnt vmcnt(4)" ::: "memory");
    } else {
      asm volatile("s_waitcnt vmcnt(0)" ::: "memory");
    }
    __builtin_amdgcn_s_barrier();
    s16x8 af[4], bfr[4];
    #pragma unroll
    for (int mi = 0; mi < 4; mi++)
      af[mi] = *reinterpret_cast<const s16x8*>(&As[cur][(wr*64 + mi*16 + row16)*BK + (kb^rperm)*8]);
    #pragma unroll
    for (int ni = 0; ni < 4; ni++)
      bfr[ni] = *reinterpret_cast<const s16x8*>(&Bs[cur][(wc*64 + ni*16 + row16)*BK + (kb^rperm)*8]);
    __builtin_amdgcn_s_setprio(1);
    #pragma unroll
    for (int mi = 0; mi < 4; mi++)
      #pragma unroll
      for (int ni = 0; ni < 4; ni++)
        acc[mi][ni] = __builtin_amdgcn_mfma_f32_16x16x32_bf16(af[mi], bfr[ni], acc[mi][ni], 0, 0, 0);
    __builtin_amdgcn_s_setprio(0);
    __builtin_amdgcn_s_barrier();
  }
  __syncthreads();   // full fence before wbuf aliases As/Bs

  // ---- epilogue: cross-wave wbuf -> 512 B-segment stores (R8-verified) ----
  int c32 = t & 31;
  int cb4 = ct*128 + c32*4;
  float sc4[4], of4[4], cn4[4], bc4[4];
  #pragma unroll
  for (int j = 0; j < 4; j++){
    int c = cb4 + j;
    bool v = (c < CH);
    float w1v = v ? w1[c] : 0.f, w2v = v ? w2[c] : 0.f;
    float b1v = v ? b1[c] : 0.f, b2v = v ? b2[c] : 0.f;
    float mv  = v ? meanw[(size_t)b*CP + c] : 0.f;
    sc4[j] = 1.f + w1v*w2v;
    of4[j] = w1v*b2v + b1v;
    cn4[j] = mv;
    bc4[j] = 1.4142135623730951f * sc4[j] * mv;
  }
  bool cfull = (cb4 + 3 < CH);
  size_t outb = (size_t)b*PRED*CH;
  int prow = t >> 5;   // 0..7

  #pragma unroll
  for (int ni = 0; ni < 4; ni++){
    #pragma unroll
    for (int mi = 0; mi < 4; mi++)
      #pragma unroll
      for (int r = 0; r < 4; r++)
        wbuf[wc][row16][wr*64 + mi*16 + kb*4 + r] = acc[mi][ni][r];
    __syncthreads();
    #pragma unroll
    for (int k = 0; k < 4; k++){
      int wcp   = k >> 1;
      int p_loc = (k & 1)*8 + prow;
      int p = pt*128 + wcp*64 + ni*16 + p_loc;
      if (p < PRED){
        f32x4 g = *reinterpret_cast<const f32x4*>(&wbuf[wcp][p_loc][c32*4]);
        float sp = Srow[p], sl = Slo[p], bl = blo[p];
        f32x4 ov;
        #pragma unroll
        for (int j = 0; j < 4; j++)
          ov[j] = sc4[j]*g[j] + (cn4[j] - bc4[j]*sp + of4[j]*sl + bl);
        float* op = &out[outb + (size_t)p*CH + cb4];
        if (cfull){
          *reinterpret_cast<f32x4*>(op) = ov;
        } else {
          #pragma unroll
          for (int j = 0; j < 4; j++)
            if (cb4 + j < CH) op[j] = ov[j];
        }
      }
    }
    __syncthreads();
  }
}

extern "C" void kernel_launch(void* const* d_in, const int* in_sizes, int n_in,
                              void* d_out, int out_size, void* d_ws, size_t ws_size,
                              hipStream_t stream)
{
  const float* x   = (const float*)d_in[0];
  const float* w1  = (const float*)d_in[1];
  const float* b1  = (const float*)d_in[2];
  const float* w2  = (const float*)d_in[3];
  const float* b2  = (const float*)d_in[4];
  const float* Wlo = (const float*)d_in[5];
  const float* blo = (const float*)d_in[6];
  float* out = (float*)d_out;

  char* ws = (char*)d_ws;
  float* Dm    = (float*)(ws);
  u16*   Mbf   = (u16*)(ws + 518400);
  float* Srow  = (float*)(ws + 518400 + 589824);
  float* Slo   = (float*)(ws + 518400 + 589824 + 3072);
  u16*   pairB = (u16*)(ws + 518400 + 589824 + 6144);
  float* meanw = (float*)(ws + 518400 + 589824 + 6144 + 44040192);

  k_dct<<<dim3((NIN*NIN + 255)/256), dim3(256), 0, stream>>>(Dm);
  k_mmat<<<dim3(PP), dim3(384), 0, stream>>>(Wlo, Dm, Mbf, Srow, Slo);
  k_pre<<<dim3(CP/64, NB), dim3(256), 0, stream>>>(x, pairB, meanw);
  k_gemm<<<dim3(6*7*NB), dim3(256), 0, stream>>>(pairB, Mbf, Srow, Slo, meanw,
                                                 w1, b1, w2, b2, blo, out);
}

// Round 10
// 154.629 us; speedup vs baseline: 1.0770x; 1.0770x over previous
//
#include <hip/hip_runtime.h>
#include <hip/hip_bf16.h>
#include <cstdint>

#define SEQ   720
#define PRED  720
#define CH    862
#define NB    64
#define NIN   360   // IN_LEN
#define KP    384   // padded K (12 * 32)
#define CP    896   // padded channels (7 * 128)
#define PP    768   // padded pred (6 * 128)
#define BK    32

typedef __attribute__((ext_vector_type(8))) short s16x8;
typedef __attribute__((ext_vector_type(4))) float f32x4;
typedef __attribute__((ext_vector_type(2))) float f32x2;
typedef unsigned int u32;
typedef unsigned short u16;

__device__ __forceinline__ u16 to_bf16u(float f){
  __hip_bfloat16 h = __float2bfloat16(f);
  return *reinterpret_cast<u16*>(&h);
}

// ---------------- Kernel A: DCT-II ortho matrix D[n][m], n,m in [0,360) ----------------
__global__ __launch_bounds__(256) void k_dct(float* __restrict__ Dm){
  int idx = blockIdx.x*256 + threadIdx.x;
  if (idx >= NIN*NIN) return;
  int n = idx / NIN, m = idx % NIN;
  int r = ((2*m+1)*n) % (4*NIN);
  float ang = (float)r * (float)(3.14159265358979323846 / 720.0);
  float v = cosf(ang) * 0.07453559924999299f;   // sqrt(2/360)
  if (n == 0) v *= 0.7071067811865476f;
  Dm[idx] = v;
}

// ---------------- Kernel B: M[p][m] = (1/N) sum_n Wlo[p][n] * D[n][m]  (bf16) + row sums ----------------
__global__ __launch_bounds__(384) void k_mmat(const float* __restrict__ Wlo, const float* __restrict__ Dm,
                                              u16* __restrict__ Mbf, float* __restrict__ Srow,
                                              float* __restrict__ Slo){
  int p = blockIdx.x;
  int t = threadIdx.x;
  if (p >= PRED){
    Mbf[(size_t)p*KP + t] = 0;
    if (t == 0){ Srow[p] = 0.f; Slo[p] = 0.f; }
    return;
  }
  __shared__ float Wrow[NIN];
  __shared__ float redM[6], redW[6];
  if (t < NIN) Wrow[t] = Wlo[(size_t)p*NIN + t];
  __syncthreads();
  float acc = 0.f;
  if (t < NIN){
    const float* Dc = Dm + t;
    #pragma unroll 4
    for (int n = 0; n < NIN; n++) acc += Wrow[n] * Dc[(size_t)n*NIN];
    acc *= (1.0f/360.0f);
  }
  Mbf[(size_t)p*KP + t] = (t < NIN) ? to_bf16u(acc) : (u16)0;
  float mv = (t < NIN) ? acc : 0.f;
  float wv = (t < NIN) ? Wrow[t] : 0.f;
  #pragma unroll
  for (int off = 32; off > 0; off >>= 1){
    mv += __shfl_down(mv, off);
    wv += __shfl_down(wv, off);
  }
  int wid = t >> 6, lid = t & 63;
  if (lid == 0){ redM[wid] = mv; redW[wid] = wv; }
  __syncthreads();
  if (t == 0){
    float sm = 0.f, sw = 0.f;
    #pragma unroll
    for (int i = 0; i < 6; i++){ sm += redM[i]; sw += redW[i]; }
    Srow[p] = sm; Slo[p] = sw;
  }
}

// ---------------- Kernel C: pair sums -> bf16 A-matrix, two 192-row halves (25.3 KB LDS) ----------------
__global__ __launch_bounds__(256) void k_pre(const float* __restrict__ x, u16* __restrict__ pairB,
                                             float* __restrict__ meanw){
  int b  = blockIdx.y;
  int c0 = blockIdx.x * 64;
  int t  = threadIdx.x;
  int c16  = t & 15;
  int mrow = t >> 4;
  int w    = t >> 6;
  __shared__ u16  pl[192][66];     // 25.3 KB -> 6 blocks/CU, all 896 blocks co-resident
  __shared__ float red[4][64];
  const float rs2 = 0.7071067811865476f;
  int cb = c0 + c16*4;
  bool full = (cb + 3 < CH);
  const float* xb = x + (size_t)b*SEQ*CH + cb;
  float s0=0.f, s1=0.f, s2=0.f, s3=0.f;
  int rowc = t >> 2;
  int mq0  = t & 3;
  size_t rbase = ((size_t)b*CP + c0 + rowc) * KP;

  #pragma unroll 1
  for (int h = 0; h < 2; h++){
    // phase 1: pair sums for m in [192h, 192h+192) (zeros baked for m >= 360)
    #pragma unroll 1
    for (int ml = mrow; ml < 192; ml += 16){
      int m = h*192 + ml;
      float p0=0.f, p1=0.f, p2=0.f, p3=0.f;
      if (m < NIN){
        const float* r0 = xb + (size_t)(2*m)*CH;
        float a0,a1,a2,a3, e0,e1,e2,e3;
        if (full){
          f32x4 va = *reinterpret_cast<const f32x4*>(r0);
          f32x2 vb = *reinterpret_cast<const f32x2*>(r0 + CH);
          f32x2 vc = *reinterpret_cast<const f32x2*>(r0 + CH + 2);
          a0=va.x; a1=va.y; a2=va.z; a3=va.w;
          e0=vb.x; e1=vb.y; e2=vc.x; e3=vc.y;
        } else {
          a0 = (cb+0<CH)? r0[0]:0.f; a1 = (cb+1<CH)? r0[1]:0.f;
          a2 = (cb+2<CH)? r0[2]:0.f; a3 = (cb+3<CH)? r0[3]:0.f;
          e0 = (cb+0<CH)? r0[CH+0]:0.f; e1 = (cb+1<CH)? r0[CH+1]:0.f;
          e2 = (cb+2<CH)? r0[CH+2]:0.f; e3 = (cb+3<CH)? r0[CH+3]:0.f;
        }
        p0=a0+e0; p1=a1+e1; p2=a2+e2; p3=a3+e3;
        s0+=p0; s1+=p1; s2+=p2; s3+=p3;
      }
      u32 lo = (u32)to_bf16u(p0*rs2) | ((u32)to_bf16u(p1*rs2) << 16);
      u32 hi = (u32)to_bf16u(p2*rs2) | ((u32)to_bf16u(p3*rs2) << 16);
      *reinterpret_cast<u32*>(&pl[ml][c16*4 + 0]) = lo;
      *reinterpret_cast<u32*>(&pl[ml][c16*4 + 2]) = hi;
    }
    __syncthreads();
    // phase 2: coalesced 16B writes of this half's 24 chunks (6 iters x 4 chunks)
    #pragma unroll
    for (int i = 0; i < 6; i++){
      int mg = mq0 + 4*i;          // chunk within half, 0..23
      u16 vals[8];
      #pragma unroll
      for (int j = 0; j < 8; j++) vals[j] = pl[mg*8 + j][rowc];
      uint4 pk;
      pk.x = (u32)vals[0] | ((u32)vals[1] << 16);
      pk.y = (u32)vals[2] | ((u32)vals[3] << 16);
      pk.z = (u32)vals[4] | ((u32)vals[5] << 16);
      pk.w = (u32)vals[6] | ((u32)vals[7] << 16);
      *reinterpret_cast<uint4*>(pairB + rbase + h*192 + (size_t)mg*8) = pk;
    }
    __syncthreads();   // pl reads done before next half overwrites
  }

  // mean reduction (sums accumulated across both halves)
  s0 += __shfl_down(s0, 32); s1 += __shfl_down(s1, 32);
  s2 += __shfl_down(s2, 32); s3 += __shfl_down(s3, 32);
  s0 += __shfl_down(s0, 16); s1 += __shfl_down(s1, 16);
  s2 += __shfl_down(s2, 16); s3 += __shfl_down(s3, 16);
  if ((t & 63) < 16){
    f32x4 rv; rv.x=s0; rv.y=s1; rv.z=s2; rv.w=s3;
    *reinterpret_cast<f32x4*>(&red[w][c16*4]) = rv;
  }
  __syncthreads();
  if (t < 64){
    float mean = (red[0][t] + red[1][t] + red[2][t] + red[3][t]) * (1.0f/SEQ);
    meanw[(size_t)b*CP + c0 + t] = mean;
  }
}

// ---------------- Kernel D: GEMM G = A * M^T (+ fused epilogue) — R8-verified ----------------
#define GLOAD_LDS16(gp, lp_) __builtin_amdgcn_global_load_lds( \
    (const __attribute__((address_space(1))) u32*)(gp), \
    (__attribute__((address_space(3))) u32*)(lp_), 16, 0, 0)

__global__ __launch_bounds__(256, 4) void k_gemm(const u16* __restrict__ Apack, const u16* __restrict__ Mbf,
                                              const float* __restrict__ Srow, const float* __restrict__ Slo,
                                              const float* __restrict__ meanw,
                                              const float* __restrict__ w1, const float* __restrict__ b1,
                                              const float* __restrict__ w2, const float* __restrict__ b2,
                                              const float* __restrict__ blo,
                                              float* __restrict__ out){
  // XCD-aware bijective swizzle: 2688 = 8 * 336.
  int bid = blockIdx.x;
  int idx = (bid & 7) * 336 + (bid >> 3);
  int pt  = idx % 6;
  int rem = idx / 6;
  int ct  = rem % 7;
  int b   = rem / 7;

  int t  = threadIdx.x;
  int w  = t >> 6, l = t & 63;
  int wr = w >> 1, wc = w & 1;

  // 32 KB union: As[2]+Bs[2] during K-loop; wbuf (16.9 KB) during epilogue.
  __shared__ __align__(16) char smem[32768];
  u16 (*As)[128*BK] = reinterpret_cast<u16(*)[128*BK]>(smem);
  u16 (*Bs)[128*BK] = reinterpret_cast<u16(*)[128*BK]>(smem + 16384);
  float (*wbuf)[16][132] = reinterpret_cast<float(*)[16][132]>(smem);  // [wc][p16][c128+pad]

  f32x4 acc[4][4] = {};

  const u16* Abase = Apack + ((size_t)b*CP + (size_t)ct*128) * KP;
  const u16* Bbase = Mbf + (size_t)pt*128*KP;
  int srow = t >> 2;
  int squad = t & 3;
  int row16 = l & 15, kb = l >> 4;
  int sperm = (srow >> 1) & 3;        // write-side XOR swizzle (global src pre-swizzled)
  int rperm = (row16 >> 1) & 3;       // read-side XOR swizzle (same involution)

#define STAGE(bufi, k0) do { \
    GLOAD_LDS16(Abase + (size_t)(srow)*KP + (k0) + ((squad^sperm))*8,      &As[bufi][(srow)*BK + squad*8]); \
    GLOAD_LDS16(Abase + (size_t)(64 + srow)*KP + (k0) + ((squad^sperm))*8, &As[bufi][(64 + srow)*BK + squad*8]); \
    GLOAD_LDS16(Bbase + (size_t)(srow)*KP + (k0) + ((squad^sperm))*8,      &Bs[bufi][(srow)*BK + squad*8]); \
    GLOAD_LDS16(Bbase + (size_t)(64 + srow)*KP + (k0) + ((squad^sperm))*8, &Bs[bufi][(64 + srow)*BK + squad*8]); \
  } while(0)

  STAGE(0, 0);
  for (int ks = 0; ks < 12; ks++){
    int cur = ks & 1;
    if (ks < 11){
      STAGE(cur ^ 1, (ks + 1) * BK);
      asm volatile("s_waitcnt vmcnt(4)" ::: "memory");
    } else {
      asm volatile("s_waitcnt vmcnt(0)" ::: "memory");
    }
    __builtin_amdgcn_s_barrier();
    s16x8 af[4], bfr[4];
    #pragma unroll
    for (int mi = 0; mi < 4; mi++)
      af[mi] = *reinterpret_cast<const s16x8*>(&As[cur][(wr*64 + mi*16 + row16)*BK + (kb^rperm)*8]);
    #pragma unroll
    for (int ni = 0; ni < 4; ni++)
      bfr[ni] = *reinterpret_cast<const s16x8*>(&Bs[cur][(wc*64 + ni*16 + row16)*BK + (kb^rperm)*8]);
    __builtin_amdgcn_s_setprio(1);
    #pragma unroll
    for (int mi = 0; mi < 4; mi++)
      #pragma unroll
      for (int ni = 0; ni < 4; ni++)
        acc[mi][ni] = __builtin_amdgcn_mfma_f32_16x16x32_bf16(af[mi], bfr[ni], acc[mi][ni], 0, 0, 0);
    __builtin_amdgcn_s_setprio(0);
    __builtin_amdgcn_s_barrier();
  }
  __syncthreads();   // full fence before wbuf aliases As/Bs

  // ---- epilogue: cross-wave wbuf -> 512 B-segment stores ----
  int c32 = t & 31;
  int cb4 = ct*128 + c32*4;
  float sc4[4], of4[4], cn4[4], bc4[4];
  #pragma unroll
  for (int j = 0; j < 4; j++){
    int c = cb4 + j;
    bool v = (c < CH);
    float w1v = v ? w1[c] : 0.f, w2v = v ? w2[c] : 0.f;
    float b1v = v ? b1[c] : 0.f, b2v = v ? b2[c] : 0.f;
    float mv  = v ? meanw[(size_t)b*CP + c] : 0.f;
    sc4[j] = 1.f + w1v*w2v;
    of4[j] = w1v*b2v + b1v;
    cn4[j] = mv;
    bc4[j] = 1.4142135623730951f * sc4[j] * mv;
  }
  bool cfull = (cb4 + 3 < CH);
  size_t outb = (size_t)b*PRED*CH;
  int prow = t >> 5;   // 0..7

  #pragma unroll
  for (int ni = 0; ni < 4; ni++){
    #pragma unroll
    for (int mi = 0; mi < 4; mi++)
      #pragma unroll
      for (int r = 0; r < 4; r++)
        wbuf[wc][row16][wr*64 + mi*16 + kb*4 + r] = acc[mi][ni][r];
    __syncthreads();
    #pragma unroll
    for (int k = 0; k < 4; k++){
      int wcp   = k >> 1;
      int p_loc = (k & 1)*8 + prow;
      int p = pt*128 + wcp*64 + ni*16 + p_loc;
      if (p < PRED){
        f32x4 g = *reinterpret_cast<const f32x4*>(&wbuf[wcp][p_loc][c32*4]);
        float sp = Srow[p], sl = Slo[p], bl = blo[p];
        f32x4 ov;
        #pragma unroll
        for (int j = 0; j < 4; j++)
          ov[j] = sc4[j]*g[j] + (cn4[j] - bc4[j]*sp + of4[j]*sl + bl);
        float* op = &out[outb + (size_t)p*CH + cb4];
        if (cfull){
          *reinterpret_cast<f32x4*>(op) = ov;
        } else {
          #pragma unroll
          for (int j = 0; j < 4; j++)
            if (cb4 + j < CH) op[j] = ov[j];
        }
      }
    }
    __syncthreads();
  }
}

extern "C" void kernel_launch(void* const* d_in, const int* in_sizes, int n_in,
                              void* d_out, int out_size, void* d_ws, size_t ws_size,
                              hipStream_t stream)
{
  const float* x   = (const float*)d_in[0];
  const float* w1  = (const float*)d_in[1];
  const float* b1  = (const float*)d_in[2];
  const float* w2  = (const float*)d_in[3];
  const float* b2  = (const float*)d_in[4];
  const float* Wlo = (const float*)d_in[5];
  const float* blo = (const float*)d_in[6];
  float* out = (float*)d_out;

  char* ws = (char*)d_ws;
  float* Dm    = (float*)(ws);
  u16*   Mbf   = (u16*)(ws + 518400);
  float* Srow  = (float*)(ws + 518400 + 589824);
  float* Slo   = (float*)(ws + 518400 + 589824 + 3072);
  u16*   pairB = (u16*)(ws + 518400 + 589824 + 6144);
  float* meanw = (float*)(ws + 518400 + 589824 + 6144 + 44040192);

  k_dct<<<dim3((NIN*NIN + 255)/256), dim3(256), 0, stream>>>(Dm);
  k_mmat<<<dim3(PP), dim3(384), 0, stream>>>(Wlo, Dm, Mbf, Srow, Slo);
  k_pre<<<dim3(CP/64, NB), dim3(256), 0, stream>>>(x, pairB, meanw);
  k_gemm<<<dim3(6*7*NB), dim3(256), 0, stream>>>(pairB, Mbf, Srow, Slo, meanw,
                                                 w1, b1, w2, b2, blo, out);
}